// Round 22
// baseline (199.901 us; speedup 1.0000x reference)
//
#include <hip/hip_runtime.h>
#include <hip/hip_bf16.h>

// Flash-attention fwd, fp32 in/out, bf16 MFMA compute.
// B=64, L=1024, D=64. scale=1/sqrt(512). mask(int32)!=0 -> -1e9.
// R22 = R16 (best, 98.1us) with SINGLE-buffered K/V LDS:
//  - LDS 46.1 -> 27.6 KB => 4 blocks/CU (grid max) = 16 waves/CU, +33% TLP
//    (R16 was LDS-capped at 3 blocks; occupancy was the measured deficit)
//  - cost: 2 barriers/tile, but the write window is short (cvt + 8 ds_writes
//    from ALREADY-HELD registers -- loads were issued at body top and pinned)
//  - everything else byte-identical to R16: XCD decode, held K/V prefetch,
//    2-deep mask ring, mask-as-C-seed, invT-prefolded Q, p_lds PV path.

typedef __attribute__((ext_vector_type(4))) float f32x4;
typedef __attribute__((ext_vector_type(8))) short bf16x8;
typedef __attribute__((ext_vector_type(4))) short short4v;

constexpr int B_ = 64;
constexpr int L_ = 1024;
constexpr int D_ = 64;
constexpr int QBLK = 64;     // q rows per block (4 waves x 16)
constexpr int KV = 64;       // keys per tile
constexpr int NKV = L_ / KV; // 16 tiles
constexpr int STR = 72;      // shorts per LDS row (64 + 8 pad)
constexpr float INV_TEMP = 0.04419417382415922f; // 1/sqrt(512)
constexpr float NEG = -1e9f;

__device__ inline short f2bf(float f) {
  __hip_bfloat16 h = __float2bfloat16(f);
  short s; __builtin_memcpy(&s, &h, 2);
  return s;
}

__global__ __launch_bounds__(256, 4) void attn_fwd(
    const float* __restrict__ Q, const float* __restrict__ K,
    const float* __restrict__ V, const int* __restrict__ M,
    float* __restrict__ O)
{
  __shared__ short k_lds[KV][STR];      // 9.2 KB
  __shared__ short vt_lds[D_][STR];     // 9.2 KB
  __shared__ short p_lds[4][16][STR];   // 9.2 KB  -> 27.6 KB, 4 blocks/CU

  const int tid  = threadIdx.x;
  const int w    = tid >> 6;
  const int lane = tid & 63;
  const int g    = lane >> 4;
  const int c    = lane & 15;

  // ---- XCD-aware decode: all 16 q-tile blocks of batch b on one XCD
  const int p   = blockIdx.x;
  const int xcd = p & 7;
  const int j   = p >> 3;           // 0..127
  const int b   = xcd + 8 * (j >> 4);
  const int q0  = (j & 15) * QBLK;

  // ---- Q fragment (B operand of swapped QK^T), invT pre-folded
  bf16x8 qf[2];
  {
    const float* qp = Q + ((size_t)b * L_ + q0 + w * 16 + c) * D_ + g * 8;
#pragma unroll
    for (int ks = 0; ks < 2; ++ks) {
      f32x4 x0 = *(const f32x4*)(qp + ks * 32);
      f32x4 x1 = *(const f32x4*)(qp + ks * 32 + 4);
      bf16x8 t;
      t[0] = f2bf(x0[0] * INV_TEMP); t[1] = f2bf(x0[1] * INV_TEMP);
      t[2] = f2bf(x0[2] * INV_TEMP); t[3] = f2bf(x0[3] * INV_TEMP);
      t[4] = f2bf(x1[0] * INV_TEMP); t[5] = f2bf(x1[1] * INV_TEMP);
      t[6] = f2bf(x1[2] * INV_TEMP); t[7] = f2bf(x1[3] * INV_TEMP);
      qf[ks] = t;
    }
  }

  const float* Kb = K + (size_t)b * L_ * D_;
  const float* Vb = V + (size_t)b * L_ * D_;
  // mask, swapped layout: lane's own row q=w*16+c, keys f*16+4g+0..3 per tile
  const int* mlane = M + (size_t)b * L_ * L_ + (size_t)(q0 + w * 16 + c) * L_ + 4 * g;

  f32x4 kreg[4], vreg[4];             // HELD through compute (pinned below)
  int4  mA[4], mB[4];                 // mask ring, 2 tiles deep
  const int vkey4 = (tid & 15) * 4;   // V staging: 4x4 block per thread
  const int vd4   = (tid >> 4) * 4;

  auto load_kv = [&](int t) {
    const float* ksrc = Kb + (size_t)(t * KV) * D_;
    const float* vsrc = Vb + (size_t)(t * KV) * D_;
#pragma unroll
    for (int i = 0; i < 4; ++i) {
      kreg[i] = *(const f32x4*)(ksrc + (size_t)(tid + i * 256) * 4);
      vreg[i] = *(const f32x4*)(vsrc + (size_t)(vkey4 + i) * D_ + vd4);
    }
  };
  auto load_m = [&](int t, int4 (&mr)[4]) {
#pragma unroll
    for (int f = 0; f < 4; ++f) mr[f] = *(const int4*)(mlane + t * KV + f * 16);
  };
  auto write_kv = [&]() {             // cvt + ds_write from held regs
#pragma unroll
    for (int i = 0; i < 4; ++i) {
      const int idx = tid + i * 256;
      short4v ks4 = { f2bf(kreg[i][0]), f2bf(kreg[i][1]),
                      f2bf(kreg[i][2]), f2bf(kreg[i][3]) };
      *(short4v*)&k_lds[idx >> 4][(idx & 15) * 4] = ks4;
      const int jj = (i + (tid >> 4)) & 3;   // rotated row order (bank spread)
      short4v vt4 = { f2bf(vreg[0][jj]), f2bf(vreg[1][jj]),
                      f2bf(vreg[2][jj]), f2bf(vreg[3][jj]) };
      *(short4v*)&vt_lds[vd4 + jj][vkey4] = vt4;
    }
  };

  f32x4 acc[4];
#pragma unroll
  for (int i = 0; i < 4; ++i) acc[i] = (f32x4){0.f, 0.f, 0.f, 0.f};
  float m_run = -INFINITY;  // per-lane, q-row = w*16+c
  float l_run = 0.f;

  // prologue: tile 0 staged; masks for tiles 0,1 in flight (2-deep)
  load_kv(0);
  write_kv();
  load_m(0, mA);
  load_m(1, mB);
  __syncthreads();

  auto body = [&](int t, int4 (&mbuf)[4], bool refill) {
    const bool has_next = (t + 1 < NKV);
    if (has_next) load_kv(t + 1);      // issue early, HELD through compute
    int4 mc[4];
#pragma unroll
    for (int f = 0; f < 4; ++f) mc[f] = mbuf[f];   // consume (reg moves)
    if (refill) load_m(t + 2, mbuf);   // refill same buffer: 2-deep ring
    __builtin_amdgcn_sched_barrier(0); // PIN: loads stay above compute

    // ---- mask bias as MFMA C-seed (fills the lgkmcnt wait shadow)
    f32x4 sc[4];
#pragma unroll
    for (int f = 0; f < 4; ++f) {
      sc[f][0] = mc[f].x ? NEG : 0.0f;
      sc[f][1] = mc[f].y ? NEG : 0.0f;
      sc[f][2] = mc[f].z ? NEG : 0.0f;
      sc[f][3] = mc[f].w ? NEG : 0.0f;
    }

    // ---- S^T = K (Q*invT)^T + bias : C row = key = f*16+g*4+r, col = q = c
#pragma unroll
    for (int f = 0; f < 4; ++f) {
      f32x4 a = sc[f];
#pragma unroll
      for (int ks = 0; ks < 2; ++ks) {
        bf16x8 kf = *(const bf16x8*)&k_lds[f * 16 + c][ks * 32 + g * 8];
        a = __builtin_amdgcn_mfma_f32_16x16x32_bf16(kf, qf[ks], a, 0, 0, 0);
      }
      sc[f] = a;
    }

    // ---- online softmax, per-lane row (16 in-lane keys x 4 lane-groups)
    float x = sc[0][0];
#pragma unroll
    for (int f = 0; f < 4; ++f)
#pragma unroll
      for (int r = 0; r < 4; ++r) x = fmaxf(x, sc[f][r]);
    x = fmaxf(x, __shfl_xor(x, 16, 64));
    x = fmaxf(x, __shfl_xor(x, 32, 64));
    const float m_new = fmaxf(m_run, x);
    const float alpha = __expf(m_run - m_new);
    float s = 0.f;
#pragma unroll
    for (int f = 0; f < 4; ++f)
#pragma unroll
      for (int r = 0; r < 4; ++r) {
        sc[f][r] = __expf(sc[f][r] - m_new);
        s += sc[f][r];
      }
    s += __shfl_xor(s, 16, 64);
    s += __shfl_xor(s, 32, 64);
    l_run = l_run * alpha + s;
    m_run = m_new;

    // ---- rescale acc: acc rows are q=g*4+r -> alpha from lane c'=g*4+r
    float ar[4];
#pragma unroll
    for (int r = 0; r < 4; ++r)
      ar[r] = __shfl(alpha, (lane & 48) | (g * 4 + r), 64);
#pragma unroll
    for (int fd = 0; fd < 4; ++fd)
#pragma unroll
      for (int r = 0; r < 4; ++r) acc[fd][r] *= ar[r];

    // ---- P -> LDS: lane owns P[q=c][keys f*16+4g+0..3] -> one b64 per f
#pragma unroll
    for (int f = 0; f < 4; ++f) {
      short4v pk = { f2bf(sc[f][0]), f2bf(sc[f][1]),
                     f2bf(sc[f][2]), f2bf(sc[f][3]) };
      *(short4v*)&p_lds[w][c][f * 16 + 4 * g] = pk;
    }

    // ---- O += P V
#pragma unroll
    for (int ks = 0; ks < 2; ++ks) {
      bf16x8 pa = *(const bf16x8*)&p_lds[w][c][ks * 32 + g * 8];
#pragma unroll
      for (int fd = 0; fd < 4; ++fd) {
        bf16x8 vb = *(const bf16x8*)&vt_lds[fd * 16 + c][ks * 32 + g * 8];
        acc[fd] = __builtin_amdgcn_mfma_f32_16x16x32_bf16(pa, vb, acc[fd], 0, 0, 0);
      }
    }

    // ---- single-buffer flip: drain readers, short cvt+write window, publish
    if (has_next) {
      __syncthreads();
      write_kv();
      __syncthreads();
    }
  };

  for (int tt = 0; tt < NKV; tt += 2) {
    body(tt,     mA, tt + 2 < NKV);   // consume m(tt),   refill -> m(tt+2)
    body(tt + 1, mB, tt + 3 < NKV);   // consume m(tt+1), refill -> m(tt+3)
  }

  // ---- epilogue: acc[fd][r] = O[q=g*4+r][d=fd*16+c]; l lives at lane c'=q
  const float li = 1.0f / l_run;
  float lr[4];
#pragma unroll
  for (int r = 0; r < 4; ++r)
    lr[r] = __shfl(li, (lane & 48) | (g * 4 + r), 64);
  float* orow = O + ((size_t)b * L_ + q0 + w * 16 + g * 4) * D_;
#pragma unroll
  for (int fd = 0; fd < 4; ++fd)
#pragma unroll
    for (int r = 0; r < 4; ++r)
      orow[(size_t)r * D_ + fd * 16 + c] = acc[fd][r] * lr[r];
}

extern "C" void kernel_launch(void* const* d_in, const int* in_sizes, int n_in,
                              void* d_out, int out_size, void* d_ws, size_t ws_size,
                              hipStream_t stream) {
  const float* q = (const float*)d_in[0];
  const float* k = (const float*)d_in[1];
  const float* v = (const float*)d_in[2];
  const int* m = (const int*)d_in[3]; // jax bool shipped as int32
  float* o = (float*)d_out;
  attn_fwd<<<dim3(1024), 256, 0, stream>>>(q, k, v, m, o);
}

// Round 23
// 97.157 us; speedup vs baseline: 2.0575x; 2.0575x over previous
//
#include <hip/hip_runtime.h>
#include <hip/hip_bf16.h>

// Flash-attention fwd, fp32 in/out, bf16 MFMA compute.  FINAL (= R16, 98.1us).
// B=64, L=1024, D=64. scale=1/sqrt(512). mask(int32)!=0 -> -1e9.
//  - 1024 blocks x 256 thr (4 waves x 16 q-rows), 16 KV-tiles of 64
//  - XCD-aware 1D grid decode: all 16 q-tile blocks of a batch on one XCD
//    (K/V L2-resident across blocks)
//  - double-buffered K/V in LDS, ONE barrier per tile; K/V prefetch HELD in
//    registers across compute (sched_barrier(0) pinned), cvt+write at flip
//  - mask read direct global->register in swapped layout, 2-deep ring
//  - swapped QK^T (mfma(K,Q)): per-lane softmax rows, 4 shuffles/tile total
//  - P C->A relayout via per-wave p_lds round-trip (within-wave DS ordering)
// Verified plateau: split-K, shuffle-exchange, zero-barrier, single-buffer,
// QBLK=128, chain-shortening all regressed or neutral (R8-R22 ledger).

typedef __attribute__((ext_vector_type(4))) float f32x4;
typedef __attribute__((ext_vector_type(8))) short bf16x8;
typedef __attribute__((ext_vector_type(4))) short short4v;

constexpr int B_ = 64;
constexpr int L_ = 1024;
constexpr int D_ = 64;
constexpr int QBLK = 64;     // q rows per block (4 waves x 16)
constexpr int KV = 64;       // keys per tile
constexpr int NKV = L_ / KV; // 16 tiles
constexpr int STR = 72;      // shorts per LDS row (64 + 8 pad)
constexpr float INV_TEMP = 0.04419417382415922f; // 1/sqrt(512)
constexpr float NEG = -1e9f;

__device__ inline short f2bf(float f) {
  __hip_bfloat16 h = __float2bfloat16(f);
  short s; __builtin_memcpy(&s, &h, 2);
  return s;
}

__global__ __launch_bounds__(256, 3) void attn_fwd(
    const float* __restrict__ Q, const float* __restrict__ K,
    const float* __restrict__ V, const int* __restrict__ M,
    float* __restrict__ O)
{
  __shared__ short k_lds[2][KV][STR];   // 18.4 KB
  __shared__ short vt_lds[2][D_][STR];  // 18.4 KB
  __shared__ short p_lds[4][16][STR];   //  9.2 KB  -> 46.1 KB, 3 blocks/CU

  const int tid  = threadIdx.x;
  const int w    = tid >> 6;
  const int lane = tid & 63;
  const int g    = lane >> 4;
  const int c    = lane & 15;

  // ---- XCD-aware decode: all 16 q-tile blocks of batch b on one XCD
  const int p   = blockIdx.x;
  const int xcd = p & 7;
  const int j   = p >> 3;           // 0..127
  const int b   = xcd + 8 * (j >> 4);
  const int q0  = (j & 15) * QBLK;

  // ---- Q fragment (B operand of swapped QK^T): col=c -> q-row w*16+c
  bf16x8 qf[2];
  {
    const float* qp = Q + ((size_t)b * L_ + q0 + w * 16 + c) * D_ + g * 8;
#pragma unroll
    for (int ks = 0; ks < 2; ++ks) {
      f32x4 x0 = *(const f32x4*)(qp + ks * 32);
      f32x4 x1 = *(const f32x4*)(qp + ks * 32 + 4);
      bf16x8 t;
      t[0] = f2bf(x0[0]); t[1] = f2bf(x0[1]); t[2] = f2bf(x0[2]); t[3] = f2bf(x0[3]);
      t[4] = f2bf(x1[0]); t[5] = f2bf(x1[1]); t[6] = f2bf(x1[2]); t[7] = f2bf(x1[3]);
      qf[ks] = t;
    }
  }

  const float* Kb = K + (size_t)b * L_ * D_;
  const float* Vb = V + (size_t)b * L_ * D_;
  // mask, swapped layout: lane's own row q=w*16+c, keys f*16+4g+0..3 per tile
  const int* mlane = M + (size_t)b * L_ * L_ + (size_t)(q0 + w * 16 + c) * L_ + 4 * g;

  f32x4 kreg[4], vreg[4];             // HELD through compute (pinned below)
  int4  mA[4], mB[4];                 // mask ring, 2 tiles deep
  const int vkey4 = (tid & 15) * 4;   // V staging: 4x4 block per thread
  const int vd4   = (tid >> 4) * 4;

  auto load_kv = [&](int t) {
    const float* ksrc = Kb + (size_t)(t * KV) * D_;
    const float* vsrc = Vb + (size_t)(t * KV) * D_;
#pragma unroll
    for (int i = 0; i < 4; ++i) {
      kreg[i] = *(const f32x4*)(ksrc + (size_t)(tid + i * 256) * 4);
      vreg[i] = *(const f32x4*)(vsrc + (size_t)(vkey4 + i) * D_ + vd4);
    }
  };
  auto load_m = [&](int t, int4 (&mr)[4]) {
#pragma unroll
    for (int f = 0; f < 4; ++f) mr[f] = *(const int4*)(mlane + t * KV + f * 16);
  };
  auto write_kv = [&](int buf) {      // cvt + ds_write from held regs
#pragma unroll
    for (int i = 0; i < 4; ++i) {
      const int idx = tid + i * 256;
      short4v ks4 = { f2bf(kreg[i][0]), f2bf(kreg[i][1]),
                      f2bf(kreg[i][2]), f2bf(kreg[i][3]) };
      *(short4v*)&k_lds[buf][idx >> 4][(idx & 15) * 4] = ks4;
      const int jj = (i + (tid >> 4)) & 3;   // rotated row order (bank spread)
      short4v vt4 = { f2bf(vreg[0][jj]), f2bf(vreg[1][jj]),
                      f2bf(vreg[2][jj]), f2bf(vreg[3][jj]) };
      *(short4v*)&vt_lds[buf][vd4 + jj][vkey4] = vt4;
    }
  };

  f32x4 acc[4];
#pragma unroll
  for (int i = 0; i < 4; ++i) acc[i] = (f32x4){0.f, 0.f, 0.f, 0.f};
  float m_run = -INFINITY;  // per-lane, q-row = w*16+c
  float l_run = 0.f;

  // prologue: tile 0 staged; masks for tiles 0,1 in flight (2-deep)
  load_kv(0);
  write_kv(0);
  load_m(0, mA);
  load_m(1, mB);
  __syncthreads();

  auto body = [&](int t, int4 (&mbuf)[4], bool refill) {
    const int cur = t & 1;
    const bool has_next = (t + 1 < NKV);
    if (has_next) load_kv(t + 1);      // issue early, HELD through compute
    int4 mc[4];
#pragma unroll
    for (int f = 0; f < 4; ++f) mc[f] = mbuf[f];   // consume (reg moves)
    if (refill) load_m(t + 2, mbuf);   // refill same buffer: 2-deep ring
    __builtin_amdgcn_sched_barrier(0); // PIN: loads stay above compute

    // ---- S^T = K Q^T : C row = key = f*16+g*4+r, col = q = c
    f32x4 sc[4];
#pragma unroll
    for (int f = 0; f < 4; ++f) {
      f32x4 a = (f32x4){0.f, 0.f, 0.f, 0.f};
#pragma unroll
      for (int ks = 0; ks < 2; ++ks) {
        bf16x8 kf = *(const bf16x8*)&k_lds[cur][f * 16 + c][ks * 32 + g * 8];
        a = __builtin_amdgcn_mfma_f32_16x16x32_bf16(kf, qf[ks], a, 0, 0, 0);
      }
      sc[f] = a;
    }

    // ---- scale + mask from registers (lane's own row, keys f*16+4g+r)
#pragma unroll
    for (int f = 0; f < 4; ++f) {
      const int4 mm = mc[f];
      sc[f][0] = mm.x ? NEG : sc[f][0] * INV_TEMP;
      sc[f][1] = mm.y ? NEG : sc[f][1] * INV_TEMP;
      sc[f][2] = mm.z ? NEG : sc[f][2] * INV_TEMP;
      sc[f][3] = mm.w ? NEG : sc[f][3] * INV_TEMP;
    }

    // ---- online softmax, per-lane row (16 in-lane keys x 4 lane-groups)
    float x = sc[0][0];
#pragma unroll
    for (int f = 0; f < 4; ++f)
#pragma unroll
      for (int r = 0; r < 4; ++r) x = fmaxf(x, sc[f][r]);
    x = fmaxf(x, __shfl_xor(x, 16, 64));
    x = fmaxf(x, __shfl_xor(x, 32, 64));
    const float m_new = fmaxf(m_run, x);
    const float alpha = __expf(m_run - m_new);
    float s = 0.f;
#pragma unroll
    for (int f = 0; f < 4; ++f)
#pragma unroll
      for (int r = 0; r < 4; ++r) {
        sc[f][r] = __expf(sc[f][r] - m_new);
        s += sc[f][r];
      }
    s += __shfl_xor(s, 16, 64);
    s += __shfl_xor(s, 32, 64);
    l_run = l_run * alpha + s;
    m_run = m_new;

    // ---- rescale acc: acc rows are q=g*4+r -> alpha from lane c'=g*4+r
    float ar[4];
#pragma unroll
    for (int r = 0; r < 4; ++r)
      ar[r] = __shfl(alpha, (lane & 48) | (g * 4 + r), 64);
#pragma unroll
    for (int fd = 0; fd < 4; ++fd)
#pragma unroll
      for (int r = 0; r < 4; ++r) acc[fd][r] *= ar[r];

    // ---- P -> LDS: lane owns P[q=c][keys f*16+4g+0..3] -> one b64 per f
#pragma unroll
    for (int f = 0; f < 4; ++f) {
      short4v pk = { f2bf(sc[f][0]), f2bf(sc[f][1]),
                     f2bf(sc[f][2]), f2bf(sc[f][3]) };
      *(short4v*)&p_lds[w][c][f * 16 + 4 * g] = pk;
    }

    // ---- O += P V
#pragma unroll
    for (int ks = 0; ks < 2; ++ks) {
      bf16x8 pa = *(const bf16x8*)&p_lds[w][c][ks * 32 + g * 8];
#pragma unroll
      for (int fd = 0; fd < 4; ++fd) {
        bf16x8 vb = *(const bf16x8*)&vt_lds[cur][fd * 16 + c][ks * 32 + g * 8];
        acc[fd] = __builtin_amdgcn_mfma_f32_16x16x32_bf16(pa, vb, acc[fd], 0, 0, 0);
      }
    }

    // ---- stage next tile into the idle buffer (cvt+write from held regs);
    //      ONE barrier flips it (dbuf: writers don't race readers)
    if (has_next) write_kv(cur ^ 1);
    __syncthreads();
  };

  for (int tt = 0; tt < NKV; tt += 2) {
    body(tt,     mA, tt + 2 < NKV);   // consume m(tt),   refill -> m(tt+2)
    body(tt + 1, mB, tt + 3 < NKV);   // consume m(tt+1), refill -> m(tt+3)
  }

  // ---- epilogue: acc[fd][r] = O[q=g*4+r][d=fd*16+c]; l lives at lane c'=q
  const float li = 1.0f / l_run;
  float lr[4];
#pragma unroll
  for (int r = 0; r < 4; ++r)
    lr[r] = __shfl(li, (lane & 48) | (g * 4 + r), 64);
  float* orow = O + ((size_t)b * L_ + q0 + w * 16 + g * 4) * D_;
#pragma unroll
  for (int fd = 0; fd < 4; ++fd)
#pragma unroll
    for (int r = 0; r < 4; ++r)
      orow[(size_t)r * D_ + fd * 16 + c] = acc[fd][r] * lr[r];
}

extern "C" void kernel_launch(void* const* d_in, const int* in_sizes, int n_in,
                              void* d_out, int out_size, void* d_ws, size_t ws_size,
                              hipStream_t stream) {
  const float* q = (const float*)d_in[0];
  const float* k = (const float*)d_in[1];
  const float* v = (const float*)d_in[2];
  const int* m = (const int*)d_in[3]; // jax bool shipped as int32
  float* o = (float*)d_out;
  attn_fwd<<<dim3(1024), 256, 0, stream>>>(q, k, v, m, o);
}